// Round 7
// baseline (273.513 us; speedup 1.0000x reference)
//
#include <hip/hip_runtime.h>
#include <hip/hip_bf16.h>

typedef __bf16 bf16x8 __attribute__((ext_vector_type(8)));
typedef float  f32x4  __attribute__((ext_vector_type(4)));

// float -> bf16 round-to-nearest-even (finite inputs)
__device__ __forceinline__ unsigned short f2bf(float f) {
    union { float f; unsigned int u; } v; v.f = f;
    unsigned int r = v.u + 0x7FFFu + ((v.u >> 16) & 1u);
    return (unsigned short)(r >> 16);
}

__device__ __forceinline__ void async16(const unsigned short* g, unsigned short* l) {
    __builtin_amdgcn_global_load_lds(
        (const __attribute__((address_space(1))) unsigned int*)g,
        (__attribute__((address_space(3))) unsigned int*)l,
        16, 0, 0);
}

// ---------------------------------------------------------------------------
// Transpose + cast: Xt[n][m] = (bf16) X[m][n]
// ---------------------------------------------------------------------------
__global__ __launch_bounds__(256) void transpose_to_bf16(
    const float* __restrict__ X, unsigned short* __restrict__ Xt, int Mr, int Nc)
{
    __shared__ float tile[32][33];
    const int bx = blockIdx.x * 32;
    const int by = blockIdx.y * 32;
    const int tx = threadIdx.x & 31;
    const int ty = threadIdx.x >> 5;
#pragma unroll
    for (int j = 0; j < 4; ++j)
        tile[ty + j * 8][tx] = X[(size_t)(by + ty + j * 8) * Nc + bx + tx];
    __syncthreads();
#pragma unroll
    for (int j = 0; j < 4; ++j)
        Xt[(size_t)(bx + ty + j * 8) * Mr + by + tx] = f2bf(tile[tx][ty + j * 8]);
}

// ---------------------------------------------------------------------------
// Generate transform matrix (bf16), exact integer angle reduction mod 4N.
// ---------------------------------------------------------------------------
__global__ __launch_bounds__(256) void gen_mat(
    unsigned short* __restrict__ out, int Nsz, int lg, int doSin)
{
    const int flat = (int)(((size_t)blockIdx.x * 256 + threadIdx.x) * 4);
    const int u  = flat >> lg;
    const int k0 = flat & (Nsz - 1);
    const unsigned int step = 2u * (unsigned int)u + 1u;
    const unsigned int mask = 4u * (unsigned int)Nsz - 1u;
    const float scale = 3.14159265358979323846f / (2.0f * (float)Nsz);
    unsigned short o[4];
#pragma unroll
    for (int j = 0; j < 4; ++j) {
        unsigned int p = ((unsigned int)(k0 + j) * step) & mask;
        float ang = (float)p * scale;
        float v = doSin ? __sinf(ang) : __cosf(ang);
        o[j] = f2bf(v);
    }
    uint2 pack;
    pack.x = (unsigned int)o[0] | ((unsigned int)o[1] << 16);
    pack.y = (unsigned int)o[2] | ((unsigned int)o[3] << 16);
    *reinterpret_cast<uint2*>(out + flat) = pack;
}

// ---------------------------------------------------------------------------
// 256x256 8-phase (m201-faithful) BT-layout bf16 GEMM:
//   C[i][j] = sum_k P[i][k] * Q[j][k]
// BK=64, 8 waves (2Mx4N), per-wave 128x64 C. LDS: per buf, A/B each split into
// four 64-row "units"; staging half-tiles are unit-interleaved {0,2}/{1,3} so
// each region is read in exactly one phase. Per K-tile 4 phases:
//   P1: LDA(m0)+LDB(n0) [12 rd] | stage odd.Ah1->obuf | bar | lgkm0 | Q(0,0) | bar
//   P2: LDB(n1) [4 rd]          | stage t2.Ah0->buf   | bar | lgkm0 | Q(0,1) | bar
//   P3: LDA(m1) [8 rd]          | stage t2.Bh0->buf   | bar | lgkm0 | Q(1,1) | bar
//   P4:                         | stage t2.Bh1->buf   | bar |         Q(1,0) | vmcnt(6) | bar
// vmcnt(6) = 3 half-tiles in flight, waits only at P4/P8. No sched_barrier.
// ---------------------------------------------------------------------------
__device__ __forceinline__ void store_out(float* C, size_t idx, float v) { C[idx] = v; }
__device__ __forceinline__ void store_out(unsigned short* C, size_t idx, float v) { C[idx] = f2bf(v); }

#define BARRIER __builtin_amdgcn_s_barrier()
#define LGKM0 asm volatile("s_waitcnt lgkmcnt(0)" ::: "memory")
#define PRIO1 __builtin_amdgcn_s_setprio(1)
#define PRIO0 __builtin_amdgcn_s_setprio(0)

// stage one 64-row unit (u=0..3) of tile kt into buf
#define STG_A(buf, u, kt) async16(pA + (size_t)(u) * 64 * K + (size_t)(kt) * 64, \
                                  ldsA + ((buf) << 14) + ((u) << 12) + ldst)
#define STG_B(buf, u, kt) async16(pB + (size_t)(u) * 64 * K + (size_t)(kt) * 64, \
                                  ldsB + ((buf) << 14) + ((u) << 12) + ldst)

// read A fragments for m-half mh (8 x ds_read_b128)
#define LDA_H(buf, mh) do { _Pragma("unroll") for (int ms = 0; ms < 4; ++ms) { \
    const int _o = ((buf) << 14) + aOff + ((mh) << 12) + ms * 1024; \
    af[ms][0] = *(const bf16x8*)&ldsA[_o + sl0]; \
    af[ms][1] = *(const bf16x8*)&ldsA[_o + sl1]; } } while (0)

// read B fragments for n-half nh (4 x ds_read_b128)
#define LDB_H(buf, nh) do { _Pragma("unroll") for (int nn = 0; nn < 2; ++nn) { \
    const int _o = ((buf) << 14) + bOff + ((nh) << 11) + nn * 1024; \
    bfr[nh][nn][0] = *(const bf16x8*)&ldsB[_o + sl0]; \
    bfr[nh][nn][1] = *(const bf16x8*)&ldsB[_o + sl1]; } } while (0)

// one C-quadrant over full K=64: 16 MFMA
#define MFMA_Q(mh, nh) do { _Pragma("unroll") for (int ms = 0; ms < 4; ++ms) \
    _Pragma("unroll") for (int nn = 0; nn < 2; ++nn) { \
    acc[(mh) * 4 + ms][(nh) * 2 + nn] = __builtin_amdgcn_mfma_f32_16x16x32_bf16( \
        af[ms][0], bfr[nh][nn][0], acc[(mh) * 4 + ms][(nh) * 2 + nn], 0, 0, 0); \
    acc[(mh) * 4 + ms][(nh) * 2 + nn] = __builtin_amdgcn_mfma_f32_16x16x32_bf16( \
        af[ms][1], bfr[nh][nn][1], acc[(mh) * 4 + ms][(nh) * 2 + nn], 0, 0, 0); } } while (0)

// 4 phases processing K-tile in `buf`. sO: stage odd-slot (Ah1 of tile ktO
// into obuf); sS: stage tile ktS into buf. VM: vmcnt at P4 (6 steady, 0 tail).
#define HALF(buf, obuf, ktO, ktS, sO, sS, VM) do { \
    /* P1 */ LDA_H(buf, 0); LDB_H(buf, 0); \
    if (sO) { STG_A(obuf, 1, ktO); STG_A(obuf, 3, ktO); } \
    asm volatile("s_waitcnt lgkmcnt(8)" ::: "memory"); \
    BARRIER; LGKM0; PRIO1; MFMA_Q(0, 0); PRIO0; BARRIER; \
    /* P2 */ LDB_H(buf, 1); \
    if (sS) { STG_A(buf, 0, ktS); STG_A(buf, 2, ktS); } \
    BARRIER; LGKM0; PRIO1; MFMA_Q(0, 1); PRIO0; BARRIER; \
    /* P3 */ LDA_H(buf, 1); \
    if (sS) { STG_B(buf, 0, ktS); STG_B(buf, 1, ktS); } \
    BARRIER; LGKM0; PRIO1; MFMA_Q(1, 1); PRIO0; BARRIER; \
    /* P4 */ if (sS) { STG_B(buf, 2, ktS); STG_B(buf, 3, ktS); } \
    BARRIER; PRIO1; MFMA_Q(1, 0); PRIO0; \
    asm volatile("s_waitcnt vmcnt(" #VM ")" ::: "memory"); \
    BARRIER; } while (0)

template <typename OutT>
__global__ __launch_bounds__(512, 2) void gemm_bt8(
    const unsigned short* __restrict__ P,
    const unsigned short* __restrict__ Q,
    OutT* __restrict__ C,
    int Mr, int Nc, int K)
{
    __shared__ __align__(16) unsigned short ldsA[2 * 256 * 64];
    __shared__ __align__(16) unsigned short ldsB[2 * 256 * 64];

    const int tid  = threadIdx.x;
    const int lane = tid & 63;
    const int w    = tid >> 6;       // 0..7
    const int wm   = w >> 2;         // 0..1  (M half)
    const int wn   = w & 3;          // 0..3  (N quarter)

    // XCD-bijective block swizzle (gridDim.x % 8 == 0)
    const int nbx = Nc >> 8;
    const int bid = blockIdx.x;
    const int wg  = (bid & 7) * (gridDim.x >> 3) + (bid >> 3);
    const int brow = (wg / nbx) << 8;
    const int bcol = (wg % nbx) << 8;

    // staging: thread t covers row t>>3 (of a 64-row unit), 16B slot t&7,
    // source column pre-swizzled (XOR row&7) so linear LDS dest + swizzled read.
    const int srow = tid >> 3;
    const int slot = tid & 7;
    const int sxor = ((slot ^ (srow & 7)) << 3);
    const unsigned short* pA = P + (size_t)(brow + srow) * K + sxor;
    const unsigned short* pB = Q + (size_t)(bcol + srow) * K + sxor;
    const int ldst = w << 9;         // wave-uniform LDS dest (+lane*16B by HW)

    // fragment-read constants (read-side swizzle matches source-side XOR)
    const int lr = lane & 15, lk = lane >> 4, sx = lr & 7;
    const int sl0 = ((lk) ^ sx) << 3;
    const int sl1 = ((4 + lk) ^ sx) << 3;
    const int aOff = wm * 8192 + lr * 64;   // A units {wm*2, wm*2+1}
    const int bOff = wn * 4096 + lr * 64;   // B unit wn

    bf16x8 af[4][2];          // current m-half fragments
    bf16x8 bfr[2][2][2];      // both n-halves held across the tile
    f32x4 acc[8][4] = {};

    const int nt = K >> 6;    // K-tiles of 64 (even, >= 4)

    // prologue: t0 fully; t1 all but Ah1 (Ah1 staged at P1 of iter 0)
    STG_A(0, 0, 0); STG_A(0, 2, 0); STG_A(0, 1, 0); STG_A(0, 3, 0);
    STG_B(0, 0, 0); STG_B(0, 1, 0); STG_B(0, 2, 0); STG_B(0, 3, 0);
    STG_A(1, 0, 1); STG_A(1, 2, 1);
    STG_B(1, 0, 1); STG_B(1, 1, 1); STG_B(1, 2, 1); STG_B(1, 3, 1);
    asm volatile("s_waitcnt vmcnt(6)" ::: "memory");
    BARRIER;

    const int L = nt >> 1;
    for (int i = 0; i < L - 1; ++i) {
        HALF(0, 1, 2 * i + 1, 2 * i + 2, 1, 1, 6);
        HALF(1, 0, 2 * i + 2, 2 * i + 3, 1, 1, 6);
    }
    HALF(0, 1, nt - 1, 0, 1, 0, 0);
    HALF(1, 0, 0,      0, 0, 0, 0);

    // epilogue: C/D layout col=lane&15, row=(lane>>4)*4+r
    const int r0 = brow + wm * 128 + (lane >> 4) * 4;
    const int c0 = bcol + wn * 64 + (lane & 15);
#pragma unroll
    for (int m = 0; m < 8; ++m)
#pragma unroll
        for (int n = 0; n < 4; ++n)
#pragma unroll
            for (int r = 0; r < 4; ++r)
                store_out(C, (size_t)(r0 + m * 16 + r) * Nc + (c0 + n * 16), acc[m][n][r]);
}

// ---------------------------------------------------------------------------
// launch: Y = A X B^T  via  Xt = X^T;  T = A (.) Xt;  Y = T (.) B
// ---------------------------------------------------------------------------
extern "C" void kernel_launch(void* const* d_in, const int* in_sizes, int n_in,
                              void* d_out, int out_size, void* d_ws, size_t ws_size,
                              hipStream_t stream) {
    const float* X = (const float*)d_in[0];
    const int Mr = in_sizes[1] / 2;   // 4096
    const int Nc = in_sizes[2] / 2;   // 4096
    const int lgM = 31 - __builtin_clz((unsigned)Mr);
    const int lgN = 31 - __builtin_clz((unsigned)Nc);

    unsigned short* Xt   = (unsigned short*)d_ws;              // [Nc][Mr]
    unsigned short* Wmat = Xt + (size_t)Nc * Mr;               // [4096][4096] (A then B)
    unsigned short* Tmat = Wmat + (size_t)Mr * Mr;             // [Mr][Nc]

    transpose_to_bf16<<<dim3(Nc / 32, Mr / 32), 256, 0, stream>>>(X, Xt, Mr, Nc);
    gen_mat<<<(Mr * Mr / 4) / 256, 256, 0, stream>>>(Wmat, Mr, lgM, 1);

    const int nblk = (Mr / 256) * (Nc / 256);
    gemm_bt8<unsigned short><<<nblk, 512, 0, stream>>>(Wmat, Xt, Tmat, Mr, Nc, Mr);

    gen_mat<<<(Nc * Nc / 4) / 256, 256, 0, stream>>>(Wmat, Nc, lgN, 0);
    gemm_bt8<float><<<nblk, 512, 0, stream>>>(Tmat, Wmat, (float*)d_out, Mr, Nc, Nc);
}

// Round 8
// 185.176 us; speedup vs baseline: 1.4770x; 1.4770x over previous
//
#include <hip/hip_runtime.h>
#include <hip/hip_bf16.h>

typedef __bf16 bf16x8 __attribute__((ext_vector_type(8)));
typedef float  f32x4  __attribute__((ext_vector_type(4)));

// float -> bf16 round-to-nearest-even (finite inputs)
__device__ __forceinline__ unsigned short f2bf(float f) {
    union { float f; unsigned int u; } v; v.f = f;
    unsigned int r = v.u + 0x7FFFu + ((v.u >> 16) & 1u);
    return (unsigned short)(r >> 16);
}
__device__ __forceinline__ float bf2f(unsigned short h) {
    union { unsigned int u; float f; } v; v.u = ((unsigned int)h) << 16; return v.f;
}

__device__ __forceinline__ void async16(const unsigned short* g, unsigned short* l) {
    __builtin_amdgcn_global_load_lds(
        (const __attribute__((address_space(1))) unsigned int*)g,
        (__attribute__((address_space(3))) unsigned int*)l,
        16, 0, 0);
}

// ---------------------------------------------------------------------------
// Transpose + cast + even/odd row pack: Xt[n][pi(m)] = (bf16) X[m][n]
// pi(m) = m/2 for even m, 2048 + m/2 for odd m  (even rows first)
// ---------------------------------------------------------------------------
__global__ __launch_bounds__(256) void transpose_perm(
    const float* __restrict__ X, unsigned short* __restrict__ Xt, int Mr, int Nc)
{
    __shared__ float tile[32][33];
    const int bx = blockIdx.x * 32;
    const int by = blockIdx.y * 32;
    const int tx = threadIdx.x & 31;
    const int ty = threadIdx.x >> 5;
    const int half = Mr >> 1;
#pragma unroll
    for (int j = 0; j < 4; ++j)
        tile[ty + j * 8][tx] = X[(size_t)(by + ty + j * 8) * Nc + bx + tx];
    __syncthreads();
    const int m = by + tx;
    const int pim = (m & 1) ? (half + (m >> 1)) : (m >> 1);
#pragma unroll
    for (int j = 0; j < 4; ++j)
        Xt[(size_t)(bx + ty + j * 8) * Mr + pim] = f2bf(tile[tx][ty + j * 8]);
}

// ---------------------------------------------------------------------------
// Generate packed half-transform matrix W [2048][4096]:
//   col < 2048: kk = 2*col  (even part);  col >= 2048: kk = 2*(col-2048)+1
//   W[r][col] = sin(pi*kk*(2r+1)/8192)  (doSin) else cos(...)
// Exact integer phase reduction mod 16384.
// ---------------------------------------------------------------------------
__global__ __launch_bounds__(256) void gen_w(
    unsigned short* __restrict__ out, int doSin)
{
    const int flat = (int)(((size_t)blockIdx.x * 256 + threadIdx.x) * 4);
    const int r  = flat >> 12;
    const int c0 = flat & 4095;
    const unsigned int step = 2u * (unsigned int)r + 1u;
    const float scale = 3.14159265358979323846f / 8192.0f;
    unsigned short o[4];
#pragma unroll
    for (int j = 0; j < 4; ++j) {
        const int c = c0 + j;
        const unsigned int kk = (c < 2048) ? (unsigned int)(2 * c)
                                           : (unsigned int)(2 * (c - 2048) + 1);
        unsigned int p = (kk * step) & 16383u;
        float ang = (float)p * scale;
        float v = doSin ? __sinf(ang) : __cosf(ang);
        o[j] = f2bf(v);
    }
    uint2 pack;
    pack.x = (unsigned int)o[0] | ((unsigned int)o[1] << 16);
    pack.y = (unsigned int)o[2] | ((unsigned int)o[3] << 16);
    *reinterpret_cast<uint2*>(out + flat) = pack;
}

// ---------------------------------------------------------------------------
// Butterfly 1: S [2][2048][4096] bf16 (S_e, S_o)  ->  T [4096][4096] bf16
//   T[u][pi(j)]      = S_e[u][j] + S_o[u][j]
//   T[4095-u][pi(j)] = S_o[u][j] - S_e[u][j]
// pi(j) packs even j first (cols 0..2047), odd j at 2048.. (feeds stage 2).
// ---------------------------------------------------------------------------
__global__ __launch_bounds__(256) void butterfly1(
    const unsigned short* __restrict__ S, unsigned short* __restrict__ T)
{
    const int f  = (int)(((size_t)blockIdx.x * 256 + threadIdx.x) * 8);
    const int u  = f >> 12;
    const int j0 = f & 4095;
    const size_t base = (size_t)u * 4096 + j0;
    const uint4 ev = *reinterpret_cast<const uint4*>(S + base);
    const uint4 ov = *reinterpret_cast<const uint4*>(S + (size_t)2048 * 4096 + base);
    float e[8], o[8];
    e[0]=bf2f(ev.x&0xffff); e[1]=bf2f(ev.x>>16); e[2]=bf2f(ev.y&0xffff); e[3]=bf2f(ev.y>>16);
    e[4]=bf2f(ev.z&0xffff); e[5]=bf2f(ev.z>>16); e[6]=bf2f(ev.w&0xffff); e[7]=bf2f(ev.w>>16);
    o[0]=bf2f(ov.x&0xffff); o[1]=bf2f(ov.x>>16); o[2]=bf2f(ov.y&0xffff); o[3]=bf2f(ov.y>>16);
    o[4]=bf2f(ov.z&0xffff); o[5]=bf2f(ov.z>>16); o[6]=bf2f(ov.w&0xffff); o[7]=bf2f(ov.w>>16);
    float s[8], d[8];
#pragma unroll
    for (int i = 0; i < 8; ++i) { s[i] = e[i] + o[i]; d[i] = o[i] - e[i]; }
    // even j slots: indices 0,2,4,6 ; odd: 1,3,5,7
    uint2 se, so, de, dо;
    se.x = (unsigned int)f2bf(s[0]) | ((unsigned int)f2bf(s[2]) << 16);
    se.y = (unsigned int)f2bf(s[4]) | ((unsigned int)f2bf(s[6]) << 16);
    so.x = (unsigned int)f2bf(s[1]) | ((unsigned int)f2bf(s[3]) << 16);
    so.y = (unsigned int)f2bf(s[5]) | ((unsigned int)f2bf(s[7]) << 16);
    de.x = (unsigned int)f2bf(d[0]) | ((unsigned int)f2bf(d[2]) << 16);
    de.y = (unsigned int)f2bf(d[4]) | ((unsigned int)f2bf(d[6]) << 16);
    dо.x = (unsigned int)f2bf(d[1]) | ((unsigned int)f2bf(d[3]) << 16);
    dо.y = (unsigned int)f2bf(d[5]) | ((unsigned int)f2bf(d[7]) << 16);
    const int jc = j0 >> 1;            // multiple of 4
    unsigned short* Tu = T + (size_t)u * 4096;
    unsigned short* Tr = T + (size_t)(4095 - u) * 4096;
    *reinterpret_cast<uint2*>(Tu + jc)         = se;
    *reinterpret_cast<uint2*>(Tu + 2048 + jc)  = so;
    *reinterpret_cast<uint2*>(Tr + jc)         = de;
    *reinterpret_cast<uint2*>(Tr + 2048 + jc)  = dо;
}

// ---------------------------------------------------------------------------
// Butterfly 2: S2 [2][4096][2048] bf16 (E, O) -> out [4096][4096] f32
//   out[u][v]        = E[u][v] + O[u][v]
//   out[u][4095-v]   = E[u][v] - O[u][v]
// ---------------------------------------------------------------------------
__global__ __launch_bounds__(256) void butterfly2(
    const unsigned short* __restrict__ S2, float* __restrict__ out)
{
    const int f  = (int)(((size_t)blockIdx.x * 256 + threadIdx.x) * 8);
    const int u  = f >> 11;
    const int v0 = f & 2047;
    const size_t base = (size_t)u * 2048 + v0;
    const uint4 ev = *reinterpret_cast<const uint4*>(S2 + base);
    const uint4 ov = *reinterpret_cast<const uint4*>(S2 + (size_t)4096 * 2048 + base);
    float e[8], o[8];
    e[0]=bf2f(ev.x&0xffff); e[1]=bf2f(ev.x>>16); e[2]=bf2f(ev.y&0xffff); e[3]=bf2f(ev.y>>16);
    e[4]=bf2f(ev.z&0xffff); e[5]=bf2f(ev.z>>16); e[6]=bf2f(ev.w&0xffff); e[7]=bf2f(ev.w>>16);
    o[0]=bf2f(ov.x&0xffff); o[1]=bf2f(ov.x>>16); o[2]=bf2f(ov.y&0xffff); o[3]=bf2f(ov.y>>16);
    o[4]=bf2f(ov.z&0xffff); o[5]=bf2f(ov.z>>16); o[6]=bf2f(ov.w&0xffff); o[7]=bf2f(ov.w>>16);
    float* row = out + (size_t)u * 4096;
    float4 a0 = { e[0]+o[0], e[1]+o[1], e[2]+o[2], e[3]+o[3] };
    float4 a1 = { e[4]+o[4], e[5]+o[5], e[6]+o[6], e[7]+o[7] };
    *reinterpret_cast<float4*>(row + v0)     = a0;
    *reinterpret_cast<float4*>(row + v0 + 4) = a1;
    float4 r0 = { e[7]-o[7], e[6]-o[6], e[5]-o[5], e[4]-o[4] };
    float4 r1 = { e[3]-o[3], e[2]-o[2], e[1]-o[1], e[0]-o[0] };
    *reinterpret_cast<float4*>(row + 4088 - v0) = r0;
    *reinterpret_cast<float4*>(row + 4092 - v0) = r1;
}

// ---------------------------------------------------------------------------
// 256x256 BT-layout bf16 GEMM (round-6 barrier-minimal tile), z-split pair:
//   Cz[i][j] = sum_k Pz[i][k] * Qz[j][k],  z = 0/1 selects operand offsets.
// Grid fixed 256 blocks = 2 x 128 tiles. BK=64, 8 waves, LDS 128 KiB dbuf.
// ---------------------------------------------------------------------------
__device__ __forceinline__ void store_out(float* C, size_t idx, float v) { C[idx] = v; }
__device__ __forceinline__ void store_out(unsigned short* C, size_t idx, float v) { C[idx] = f2bf(v); }

#define BARRIER __builtin_amdgcn_s_barrier()
#define PRIO1 __builtin_amdgcn_s_setprio(1)
#define PRIO0 __builtin_amdgcn_s_setprio(0)

#define STG_A(buf, h, L, kt) async16(pA + (size_t)((h) * 128 + (L) * 64) * ldp + (size_t)(kt) * 64, \
                                     ldsA + ((buf) << 14) + ((h) << 13) + ((L) << 12) + ldst)
#define STG_B(buf, h, L, kt) async16(pB + (size_t)((h) * 128 + (L) * 64) * ldq + (size_t)(kt) * 64, \
                                     ldsB + ((buf) << 14) + ((h) << 13) + ((L) << 12) + ldst)

#define LDA(buf, g) do { _Pragma("unroll") for (int mm = 0; mm < 4; ++mm) { \
    af[mm][0] = *(const bf16x8*)&ldsA[((buf) << 14) + aRow + ((g) * 4 + mm) * 1024 + sl0]; \
    af[mm][1] = *(const bf16x8*)&ldsA[((buf) << 14) + aRow + ((g) * 4 + mm) * 1024 + sl1]; } } while (0)

#define LDB(buf, p) do { _Pragma("unroll") for (int nn = 0; nn < 2; ++nn) { \
    bfr[(p) * 2 + nn][0] = *(const bf16x8*)&ldsB[((buf) << 14) + bRow + (((p) * 2 + nn)) * 1024 + sl0]; \
    bfr[(p) * 2 + nn][1] = *(const bf16x8*)&ldsB[((buf) << 14) + bRow + (((p) * 2 + nn)) * 1024 + sl1]; } } while (0)

#define MFMA_Q(g, p) do { _Pragma("unroll") for (int mm = 0; mm < 4; ++mm) \
    _Pragma("unroll") for (int nn = 0; nn < 2; ++nn) { \
    acc[(g) * 4 + mm][(p) * 2 + nn] = __builtin_amdgcn_mfma_f32_16x16x32_bf16( \
        af[mm][0], bfr[(p) * 2 + nn][0], acc[(g) * 4 + mm][(p) * 2 + nn], 0, 0, 0); \
    acc[(g) * 4 + mm][(p) * 2 + nn] = __builtin_amdgcn_mfma_f32_16x16x32_bf16( \
        af[mm][1], bfr[(p) * 2 + nn][1], acc[(g) * 4 + mm][(p) * 2 + nn], 0, 0, 0); } } while (0)

#define TILE(buf, nbuf, kt, doSA, doSB, vmN) do { \
    LDA(buf, 0); LDB(buf, 0); \
    if (doSA) { STG_A(nbuf, 0, 0, (kt) + 1); STG_A(nbuf, 0, 1, (kt) + 1); } \
    PRIO1; MFMA_Q(0, 0); PRIO0; \
    LDB(buf, 1); \
    if (doSA) { STG_A(nbuf, 1, 0, (kt) + 1); STG_A(nbuf, 1, 1, (kt) + 1); } \
    PRIO1; MFMA_Q(0, 1); PRIO0; \
    asm volatile("s_waitcnt lgkmcnt(0)" ::: "memory"); \
    BARRIER; \
    LDA(buf, 1); \
    if (doSB) { STG_B(buf, 0, 0, (kt) + 2); STG_B(buf, 0, 1, (kt) + 2); } \
    PRIO1; MFMA_Q(1, 0); PRIO0; \
    if (doSB) { STG_B(buf, 1, 0, (kt) + 2); STG_B(buf, 1, 1, (kt) + 2); } \
    PRIO1; MFMA_Q(1, 1); PRIO0; \
    asm volatile("s_waitcnt vmcnt(" #vmN ")" ::: "memory"); \
    BARRIER; } while (0)

template <typename OutT>
__global__ __launch_bounds__(512, 2) void gemm_bt8(
    const unsigned short* __restrict__ P,
    const unsigned short* __restrict__ Q,
    OutT* __restrict__ C,
    int nbx, int K, int ldp, int ldq, int ldc,
    size_t poff, size_t qoff, size_t coff)
{
    __shared__ __align__(16) unsigned short ldsA[2 * 256 * 64];
    __shared__ __align__(16) unsigned short ldsB[2 * 256 * 64];

    const int tid  = threadIdx.x;
    const int lane = tid & 63;
    const int w    = tid >> 6;
    const int wm   = w >> 2;
    const int wn   = w & 3;

    // XCD-bijective swizzle over 256 blocks; z = which half-GEMM
    const int bid = blockIdx.x;
    const int wg  = (bid & 7) * (gridDim.x >> 3) + (bid >> 3);
    const int z   = wg >> 7;
    const int t   = wg & 127;
    const int brow = (t / nbx) << 8;
    const int bcol = (t % nbx) << 8;

    const unsigned short* Pz = P + (size_t)z * poff;
    const unsigned short* Qz = Q + (size_t)z * qoff;
    OutT* Cz = C + (size_t)z * coff;

    const int srow = tid >> 3;
    const int slot = tid & 7;
    const int sxor = ((slot ^ (srow & 7)) << 3);
    const unsigned short* pA = Pz + (size_t)(brow + srow) * ldp + sxor;
    const unsigned short* pB = Qz + (size_t)(bcol + srow) * ldq + sxor;
    const int ldst = w << 9;

    const int lr = lane & 15, lk = lane >> 4, sx = lr & 7;
    const int sl0 = ((lk) ^ sx) << 3;
    const int sl1 = ((4 + lk) ^ sx) << 3;
    const int aRow = (wm * 128 + lr) * 64;
    const int bRow = (wn * 64 + lr) * 64;

    bf16x8 af[4][2], bfr[4][2];
    f32x4 acc[8][4] = {};

    const int nt = K >> 6;   // 32

    STG_A(0, 0, 0, 0); STG_A(0, 0, 1, 0); STG_A(0, 1, 0, 0); STG_A(0, 1, 1, 0);
    STG_B(0, 0, 0, 0); STG_B(0, 0, 1, 0); STG_B(0, 1, 0, 0); STG_B(0, 1, 1, 0);
    STG_B(1, 0, 0, 1); STG_B(1, 0, 1, 1); STG_B(1, 1, 0, 1); STG_B(1, 1, 1, 1);
    asm volatile("s_waitcnt vmcnt(4)" ::: "memory");
    BARRIER;

    for (int i = 0; i < (nt >> 1) - 1; ++i) {
        const int t0 = 2 * i;
        TILE(0, 1, t0,     1, 1, 4);
        TILE(1, 0, t0 + 1, 1, 1, 4);
    }
    TILE(0, 1, nt - 2, 1, 0, 0);
    TILE(1, 0, nt - 1, 0, 0, 0);

    const int r0 = brow + wm * 128 + (lane >> 4) * 4;
    const int c0 = bcol + wn * 64 + (lane & 15);
#pragma unroll
    for (int m = 0; m < 8; ++m)
#pragma unroll
        for (int n = 0; n < 4; ++n)
#pragma unroll
            for (int r = 0; r < 4; ++r)
                store_out(Cz, (size_t)(r0 + m * 16 + r) * ldc + (c0 + n * 16), acc[m][n][r]);
}

// ---------------------------------------------------------------------------
// launch. Even/odd split (2x FLOP reduction per stage):
//   stage1: S_e = A_e (.) Xt_even, S_o = A_o (.) Xt_odd   (one dispatch, z-split)
//           T[u] = S_e+S_o ; T[4095-u] = S_o-S_e          (butterfly1, pi-packed)
//   stage2: E = T_even (.) B_e, O = T_odd (.) B_o         (one dispatch, z-split)
//           out[u][v] = E+O ; out[u][4095-v] = E-O        (butterfly2, f32)
// ws: R0 Xt_perm->T_perm (32MB) | R1 W1->W2 (16MB) | R2 S1->S2 (32MB) = 80MB
// ---------------------------------------------------------------------------
extern "C" void kernel_launch(void* const* d_in, const int* in_sizes, int n_in,
                              void* d_out, int out_size, void* d_ws, size_t ws_size,
                              hipStream_t stream) {
    const float* X = (const float*)d_in[0];
    const int Mr = in_sizes[1] / 2;   // 4096
    const int Nc = in_sizes[2] / 2;   // 4096

    unsigned short* R0 = (unsigned short*)d_ws;                    // [4096][4096] bf16
    unsigned short* R1 = R0 + (size_t)Mr * Nc;                     // [2048][4096] bf16
    unsigned short* R2 = R1 + (size_t)(Mr / 2) * Nc;               // [2][2048][4096] bf16

    // 1) Xt_perm[n][pi(m)] = X[m][n]
    transpose_perm<<<dim3(Nc / 32, Mr / 32), 256, 0, stream>>>(X, R0, Mr, Nc);
    // 2) W1 = [A_e | A_o] (sin)
    gen_w<<<(2048 * 4096 / 4) / 256, 256, 0, stream>>>(R1, 1);
    // 3) S1[z] = W1_z (.) Xt_z   -> [2][2048][4096] bf16
    gemm_bt8<unsigned short><<<256, 512, 0, stream>>>(
        R1, R0, R2, /*nbx=*/16, /*K=*/2048, /*ldp=*/4096, /*ldq=*/4096, /*ldc=*/4096,
        /*poff=*/2048, /*qoff=*/2048, /*coff=*/(size_t)2048 * 4096);
    // 4) T_perm (into R0; Xt dead)
    butterfly1<<<(2048 * 4096 / 8) / 256, 256, 0, stream>>>(R2, R0);
    // 5) W2 = [B_e | B_o] (cos) (into R1; W1 dead)
    gen_w<<<(2048 * 4096 / 4) / 256, 256, 0, stream>>>(R1, 0);
    // 6) S2[z] = T_z (.) W2_z   -> [2][4096][2048] bf16 (into R2; S1 dead)
    gemm_bt8<unsigned short><<<256, 512, 0, stream>>>(
        R0, R1, R2, /*nbx=*/8, /*K=*/2048, /*ldp=*/4096, /*ldq=*/4096, /*ldc=*/2048,
        /*poff=*/2048, /*qoff=*/2048, /*coff=*/(size_t)4096 * 2048);
    // 7) butterfly2 -> f32 d_out
    butterfly2<<<(4096 * 2048 / 8) / 256, 256, 0, stream>>>(R2, (float*)d_out);
}